// Round 3
// baseline (3609.166 us; speedup 1.0000x reference)
//
#include <hip/hip_runtime.h>
#include <stdint.h>

// ---------------------------------------------------------------------------
// BERT-style encoder forward, bf16 MFMA compute, f32 accumulate.
// B=32 S=256 K=6 D=768 H=12 DK=DV=64 DFF=3072 L=12 A=128 V=30000
// (Resubmission #2: Rounds 1-2 were GPUAcquisitionTimeout — no bench signal.)
// ---------------------------------------------------------------------------

typedef unsigned short u16;
typedef __attribute__((ext_vector_type(8))) __bf16 bf16x8;   // MFMA A/B operand (4 VGPR)
typedef __attribute__((ext_vector_type(4))) float f4;        // MFMA C/D operand

__device__ __forceinline__ u16 f2b(float f) {          // f32 -> bf16 RNE
  union { float f; uint32_t u; } v; v.f = f;
  uint32_t r = v.u + 0x7fffu + ((v.u >> 16) & 1u);
  return (u16)(r >> 16);
}

__device__ __forceinline__ void gload_lds16(const void* g, void* l) {
  __builtin_amdgcn_global_load_lds((const __attribute__((address_space(1))) uint32_t*)g,
                                   (__attribute__((address_space(3))) uint32_t*)l, 16, 0, 0);
}

__device__ __forceinline__ f4 mfma16(bf16x8 a, bf16x8 b, f4 c) {
  return __builtin_amdgcn_mfma_f32_16x16x32_bf16(a, b, c, 0, 0, 0);
}

// ---------------------------------------------------------------------------
// Generic bf16 GEMM: C[M,N] = A[M,K] * Bt[N,K]^T + bias (+res) (relu?) -> f32/bf16
// 128x128 tile, BK=32, 256 thr = 4 waves each 64x64, m97 structure.
// ---------------------------------------------------------------------------
template<int RELU, int RES, int WF32, int WB16>
__global__ __launch_bounds__(256, 2) void gemm_bt(
    const u16* __restrict__ A, const u16* __restrict__ Bt,
    const float* __restrict__ bias,
    const float* res, float* Cf, u16* Cb,
    int M, int N, int K)
{
  __shared__ __align__(16) u16 As[128 * 32];
  __shared__ __align__(16) u16 Bs[128 * 32];
  const int tid  = threadIdx.x;
  const int lane = tid & 63;
  const int w    = tid >> 6;
  const int wr   = w >> 1, wc = w & 1;
  const int m0   = blockIdx.x * 128;
  const int n0   = blockIdx.y * 128;

  f4 acc[4][4];
  const f4 zf = {0.f, 0.f, 0.f, 0.f};
#pragma unroll
  for (int i = 0; i < 4; ++i)
#pragma unroll
    for (int j = 0; j < 4; ++j) acc[i][j] = zf;

  // staging: chunk c = w*64 + lane + 256*i covers row c>>2, 8 elems at (c&3)*8
  const int cA  = w * 64 + lane;
  const int rA  = cA >> 2;
  const int kc8 = (cA & 3) * 8;
  const u16* gA0 = A  + (long)(m0 + rA) * K + kc8;
  const u16* gA1 = gA0 + (long)64 * K;
  const u16* gB0 = Bt + (long)(n0 + rA) * K + kc8;
  const u16* gB1 = gB0 + (long)64 * K;
  u16* lA0 = &As[w * 512];         // wave-uniform LDS bases
  u16* lA1 = &As[w * 512 + 2048];
  u16* lB0 = &Bs[w * 512];
  u16* lB1 = &Bs[w * 512 + 2048];

  const int rdA = (wr * 64 + (lane & 15)) * 32 + (lane >> 4) * 8;
  const int rdB = (wc * 64 + (lane & 15)) * 32 + (lane >> 4) * 8;

  const int nk = K >> 5;
  for (int kk = 0; kk < nk; ++kk) {
    gload_lds16(gA0, lA0);
    gload_lds16(gA1, lA1);
    gload_lds16(gB0, lB0);
    gload_lds16(gB1, lB1);
    gA0 += 32; gA1 += 32; gB0 += 32; gB1 += 32;
    asm volatile("s_waitcnt vmcnt(0)" ::: "memory");
    __syncthreads();
    bf16x8 af[4], bf[4];
#pragma unroll
    for (int mf = 0; mf < 4; ++mf) af[mf] = *(const bf16x8*)&As[rdA + mf * 512];
#pragma unroll
    for (int nf = 0; nf < 4; ++nf) bf[nf] = *(const bf16x8*)&Bs[rdB + nf * 512];
#pragma unroll
    for (int mf = 0; mf < 4; ++mf)
#pragma unroll
      for (int nf = 0; nf < 4; ++nf)
        acc[mf][nf] = mfma16(af[mf], bf[nf], acc[mf][nf]);
    __syncthreads();
  }

  const int col0 = n0 + wc * 64 + (lane & 15);
  const int row0 = m0 + wr * 64 + (lane >> 4) * 4;
#pragma unroll
  for (int mf = 0; mf < 4; ++mf) {
#pragma unroll
    for (int nf = 0; nf < 4; ++nf) {
      const int col = col0 + nf * 16;
      const float bv = bias[col];
#pragma unroll
      for (int i = 0; i < 4; ++i) {
        const long r = row0 + mf * 16 + i;
        float v = acc[mf][nf][i] + bv;
        if (RES)  v += res[r * N + col];
        if (RELU) v  = fmaxf(v, 0.0f);
        if (WF32) Cf[r * N + col] = v;
        if (WB16) Cb[r * N + col] = f2b(v);
      }
    }
  }
}

// ---------------------------------------------------------------------------
// Weight prep: transpose f32 (R x C) -> bf16 (C x R), 32x32 tiles.
// One launch per layer covers Wq,Wk,Wv -> WqkvT ; Wo -> WoT ; f1 -> F1T ; f2 -> F2T
// ---------------------------------------------------------------------------
__device__ __forceinline__ void trans_tile(const float* __restrict__ src, u16* __restrict__ dst,
                                           int R, int C, int r0, int c0, int tid,
                                           float (*tile)[33])
{
  const int tx = tid & 31, ty = tid >> 5;
#pragma unroll
  for (int i = 0; i < 4; ++i)
    tile[ty + 8 * i][tx] = src[(long)(r0 + ty + 8 * i) * C + (c0 + tx)];
  __syncthreads();
#pragma unroll
  for (int i = 0; i < 4; ++i)
    dst[(long)(c0 + ty + 8 * i) * R + (r0 + tx)] = f2b(tile[tx][ty + 8 * i]);
}

__global__ __launch_bounds__(256) void prep_weights(
    const float* Wq, const float* Wk, const float* Wv, const float* Wo,
    const float* F1, const float* F2,
    u16* WqkvT, u16* WoT, u16* F1T, u16* F2T)
{
  __shared__ float tile[32][33];
  const int bid = blockIdx.x, tid = threadIdx.x;
  if (bid < 1728) {                 // Wq/Wk/Wv (768x768) -> rows [which*768, ..) of WqkvT
    const int which = bid / 576, t = bid % 576;
    const float* src = (which == 0) ? Wq : (which == 1) ? Wk : Wv;
    trans_tile(src, WqkvT + (long)which * 768 * 768, 768, 768,
               (t / 24) * 32, (t % 24) * 32, tid, tile);
  } else if (bid < 2304) {
    const int t = bid - 1728;
    trans_tile(Wo, WoT, 768, 768, (t / 24) * 32, (t % 24) * 32, tid, tile);
  } else if (bid < 4608) {
    const int t = bid - 2304;       // f1: 768 x 3072
    trans_tile(F1, F1T, 768, 3072, (t / 96) * 32, (t % 96) * 32, tid, tile);
  } else {
    const int t = bid - 4608;       // f2: 3072 x 768
    trans_tile(F2, F2T, 3072, 768, (t / 24) * 32, (t % 24) * 32, tid, tile);
  }
}

// ---------------------------------------------------------------------------
// V transpose: qkv[b*256+kpos][1536+h*64+d] -> vT[(b*12+h)*64+d][kpos]
// ---------------------------------------------------------------------------
__global__ __launch_bounds__(256) void vtrans(const u16* __restrict__ qkv, u16* __restrict__ vT)
{
  const int bid = blockIdx.x;          // 384 heads * 16 tiles
  const int bh = bid >> 4, t = bid & 15;
  const int b = bh / 12, h = bh % 12;
  const int tk = (t >> 1) * 32, td = (t & 1) * 32;
  __shared__ u16 tile[32][34];
  const int tx = threadIdx.x & 31, ty = threadIdx.x >> 5;
#pragma unroll
  for (int i = 0; i < 4; ++i)
    tile[ty + 8 * i][tx] = qkv[(long)(b * 256 + tk + ty + 8 * i) * 2304 + 1536 + h * 64 + td + tx];
  __syncthreads();
#pragma unroll
  for (int i = 0; i < 4; ++i)
    vT[((long)(bh * 64 + td + ty + 8 * i)) * 256 + tk + tx] = tile[tx][ty + 8 * i];
}

// ---------------------------------------------------------------------------
// Flash attention per (b,h). 4 waves x 64 q-rows. KVBLK=32, online softmax.
// Q/K frags read directly from global qkv (natural layout == B^T frag layout).
// V frags from vT. P: per-wave LDS round-trip (padded, conflict-light).
// ---------------------------------------------------------------------------
__global__ __launch_bounds__(256, 2) void attn_kernel(
    const u16* __restrict__ qkv, const u16* __restrict__ vT,
    const int* __restrict__ origin, u16* __restrict__ ctx)
{
  const int bh = blockIdx.x;
  const int b = bh / 12, h = bh % 12;
  const int tid = threadIdx.x, lane = tid & 63, w = tid >> 6;
  const int g = lane >> 4, c = lane & 15;
  __shared__ float mbias[256];
  __shared__ __align__(16) u16 Ps[4][64 * 40];
  mbias[tid] = (origin[b * 256 + tid] == 0) ? -1e9f : 0.0f;
  __syncthreads();

  // Q fragments: rows w*64 + mf*16 + c, dims ks*32 + g*8 + j
  bf16x8 qf[4][2];
  const long qbase = (long)(b * 256 + w * 64 + c) * 2304 + h * 64;
#pragma unroll
  for (int mf = 0; mf < 4; ++mf)
#pragma unroll
    for (int ks = 0; ks < 2; ++ks)
      qf[mf][ks] = *(const bf16x8*)&qkv[qbase + (long)mf * 16 * 2304 + ks * 32 + g * 8];

  f4 o[4][4];
  float mrun[4][4], lrun[4][4];
  const f4 zf = {0.f, 0.f, 0.f, 0.f};
#pragma unroll
  for (int i = 0; i < 4; ++i)
#pragma unroll
    for (int j = 0; j < 4; ++j) { o[i][j] = zf; mrun[i][j] = -1e30f; lrun[i][j] = 0.f; }

  u16* ps = Ps[w];
  const float scale = 0.125f;
  for (int kc = 0; kc < 8; ++kc) {
    bf16x8 kf[2][2];
#pragma unroll
    for (int nf = 0; nf < 2; ++nf)
#pragma unroll
      for (int ks = 0; ks < 2; ++ks)
        kf[nf][ks] = *(const bf16x8*)&qkv[(long)(b * 256 + kc * 32 + nf * 16 + c) * 2304
                                          + 768 + h * 64 + ks * 32 + g * 8];
    f4 s[4][2];
#pragma unroll
    for (int mf = 0; mf < 4; ++mf)
#pragma unroll
      for (int nf = 0; nf < 2; ++nf) {
        f4 t = mfma16(qf[mf][0], kf[nf][0], zf);
        s[mf][nf] = mfma16(qf[mf][1], kf[nf][1], t);
      }
    // online softmax update (row state per (mf,i), reduce over 16 lanes)
#pragma unroll
    for (int mf = 0; mf < 4; ++mf)
#pragma unroll
      for (int i = 0; i < 4; ++i) {
        float v0 = s[mf][0][i] * scale + mbias[kc * 32 + c];
        float v1 = s[mf][1][i] * scale + mbias[kc * 32 + 16 + c];
        float rm = fmaxf(v0, v1);
        rm = fmaxf(rm, __shfl_xor(rm, 1));
        rm = fmaxf(rm, __shfl_xor(rm, 2));
        rm = fmaxf(rm, __shfl_xor(rm, 4));
        rm = fmaxf(rm, __shfl_xor(rm, 8));
        const float mn   = fmaxf(mrun[mf][i], rm);
        const float corr = __expf(mrun[mf][i] - mn);
        mrun[mf][i] = mn;
        const float p0 = __expf(v0 - mn), p1 = __expf(v1 - mn);
        s[mf][0][i] = p0; s[mf][1][i] = p1;
        float rs = p0 + p1;
        rs += __shfl_xor(rs, 1);
        rs += __shfl_xor(rs, 2);
        rs += __shfl_xor(rs, 4);
        rs += __shfl_xor(rs, 8);
        lrun[mf][i] = lrun[mf][i] * corr + rs;
#pragma unroll
        for (int df = 0; df < 4; ++df) o[mf][df][i] *= corr;
      }
    // P (D-frag layout) -> LDS -> A-frag layout
#pragma unroll
    for (int mf = 0; mf < 4; ++mf)
#pragma unroll
      for (int nf = 0; nf < 2; ++nf)
#pragma unroll
        for (int i = 0; i < 4; ++i)
          ps[(mf * 16 + g * 4 + i) * 40 + nf * 16 + c] = f2b(s[mf][nf][i]);
    bf16x8 pa[4], vb[4];
#pragma unroll
    for (int mf = 0; mf < 4; ++mf) pa[mf] = *(const bf16x8*)&ps[(mf * 16 + c) * 40 + g * 8];
#pragma unroll
    for (int df = 0; df < 4; ++df)
      vb[df] = *(const bf16x8*)&vT[(long)(bh * 64 + df * 16 + c) * 256 + kc * 32 + g * 8];
#pragma unroll
    for (int mf = 0; mf < 4; ++mf)
#pragma unroll
      for (int df = 0; df < 4; ++df)
        o[mf][df] = mfma16(pa[mf], vb[df], o[mf][df]);
  }

#pragma unroll
  for (int mf = 0; mf < 4; ++mf)
#pragma unroll
    for (int i = 0; i < 4; ++i) {
      const float inv = 1.0f / lrun[mf][i];
      const long r = (long)(b * 256 + w * 64 + mf * 16 + g * 4 + i);
#pragma unroll
      for (int df = 0; df < 4; ++df)
        ctx[r * 768 + h * 64 + df * 16 + c] = f2b(o[mf][df][i] * inv);
    }
}

// ---------------------------------------------------------------------------
// LayerNorm over D=768, f32 in -> bf16 out. One block per row.
// ---------------------------------------------------------------------------
__global__ __launch_bounds__(256) void ln_kernel(const float* __restrict__ x,
    const float* __restrict__ gam, const float* __restrict__ bet, u16* __restrict__ out)
{
  const int row = blockIdx.x, tid = threadIdx.x;
  const int lane = tid & 63, w = tid >> 6;
  const float* xr = x + (long)row * 768;
  const float v0 = xr[tid], v1 = xr[tid + 256], v2 = xr[tid + 512];
  float s = v0 + v1 + v2;
#pragma unroll
  for (int off = 1; off < 64; off <<= 1) s += __shfl_xor(s, off);
  __shared__ float r1[4], r2[4];
  if (lane == 0) r1[w] = s;
  __syncthreads();
  const float mu = (r1[0] + r1[1] + r1[2] + r1[3]) * (1.0f / 768.0f);
  const float d0 = v0 - mu, d1 = v1 - mu, d2 = v2 - mu;
  float q = d0 * d0 + d1 * d1 + d2 * d2;
#pragma unroll
  for (int off = 1; off < 64; off <<= 1) q += __shfl_xor(q, off);
  if (lane == 0) r2[w] = q;
  __syncthreads();
  const float var = (r2[0] + r2[1] + r2[2] + r2[3]) * (1.0f / 768.0f);
  const float rs = rsqrtf(var + 1e-5f);
  out[(long)row * 768 + tid]       = f2b(d0 * rs * gam[tid]       + bet[tid]);
  out[(long)row * 768 + tid + 256] = f2b(d1 * rs * gam[tid + 256] + bet[tid + 256]);
  out[(long)row * 768 + tid + 512] = f2b(d2 * rs * gam[tid + 512] + bet[tid + 512]);
}

// ---------------------------------------------------------------------------
// Front-end: w_eff = sa_W @ sm_W (fold the linear soft-attention scorer)
// ---------------------------------------------------------------------------
__global__ void weff_kernel(const float* __restrict__ saW, const float* __restrict__ sab,
                            const float* __restrict__ smW, const float* __restrict__ smb,
                            float* weff, float* beff)
{
  const int d = blockIdx.x * 256 + threadIdx.x;   // grid 3 -> d in [0,768)
  float acc = 0.f;
  for (int a = 0; a < 128; ++a) acc += saW[d * 128 + a] * smW[a];
  weff[d] = acc;
  if (d == 0) {
    float bb = smb[0];
    for (int a = 0; a < 128; ++a) bb += sab[a] * smW[a];
    beff[0] = bb;
  }
}

// Embedding gather + K=6 soft-attention + positional add -> x (f32) and xb (bf16)
__global__ __launch_bounds__(256) void embed_kernel(
    const int* __restrict__ ids, const float* __restrict__ tok, const float* __restrict__ pos,
    const float* __restrict__ weff, const float* __restrict__ beff,
    float* __restrict__ x, u16* __restrict__ xb)
{
  const int m = blockIdx.x;           // b*256 + s
  const int s = m & 255;
  const int tid = threadIdx.x, lane = tid & 63, w = tid >> 6;
  __shared__ float emb[6][768];
  __shared__ float hred[6][4];
  const int* idp = ids + m * 6;
  float part[6];
#pragma unroll
  for (int k = 0; k < 6; ++k) {
    const float* e = tok + (long)idp[k] * 768;
    float p = 0.f;
#pragma unroll
    for (int j = 0; j < 3; ++j) {
      const int d = tid + j * 256;
      const float val = e[d];
      emb[k][d] = val;
      p += val * weff[d];
    }
    part[k] = p;
  }
#pragma unroll
  for (int k = 0; k < 6; ++k) {
    float p = part[k];
#pragma unroll
    for (int off = 1; off < 64; off <<= 1) p += __shfl_xor(p, off);
    if (lane == 0) hred[k][w] = p;
  }
  __syncthreads();
  float hv[6], mx = -1e30f;
#pragma unroll
  for (int k = 0; k < 6; ++k) {
    hv[k] = hred[k][0] + hred[k][1] + hred[k][2] + hred[k][3] + beff[0];
    mx = fmaxf(mx, hv[k]);
  }
  float esum = 0.f;
#pragma unroll
  for (int k = 0; k < 6; ++k) { hv[k] = __expf(hv[k] - mx); esum += hv[k]; }
  const float inv = 1.0f / esum;
#pragma unroll
  for (int j = 0; j < 3; ++j) {
    const int d = tid + j * 256;
    float acc = pos[s * 768 + d];
#pragma unroll
    for (int k = 0; k < 6; ++k) acc += hv[k] * inv * emb[k][d];
    x[(long)m * 768 + d] = acc;
    xb[(long)m * 768 + d] = f2b(acc);
  }
}

__global__ void pack_bqkv(const float* __restrict__ bq, const float* __restrict__ bk,
                          const float* __restrict__ bv, float* __restrict__ bqkv)
{
  const int l = blockIdx.x;
  for (int n = threadIdx.x; n < 2304; n += 256) {
    float v = (n < 768) ? bq[l * 768 + n] : (n < 1536) ? bk[l * 768 + n - 768]
                                                       : bv[l * 768 + n - 1536];
    bqkv[l * 2304 + n] = v;
  }
}

// Final head: rep = x[:,0,:]; logits = relu(rep@t1W+t1b)@t2W+t2b. f32.
__global__ __launch_bounds__(256) void head_kernel(const float* __restrict__ x,
    const float* __restrict__ t1W, const float* __restrict__ t1b,
    const float* __restrict__ t2W, const float* __restrict__ t2b,
    float* __restrict__ out)
{
  const int b = blockIdx.x, tid = threadIdx.x;
  __shared__ float rep[768];
  __shared__ float hbuf[384];
  const float* xr = x + (long)b * 256 * 768;     // row b*256
  for (int d = tid; d < 768; d += 256) {
    const float v = xr[d];
    rep[d] = v;
    out[64 + b * 768 + d] = v;                   // rep output
  }
  __syncthreads();
  for (int j = tid; j < 384; j += 256) {
    float acc = t1b[j];
    for (int d = 0; d < 768; ++d) acc += rep[d] * t1W[(long)d * 384 + j];
    hbuf[j] = fmaxf(acc, 0.0f);
  }
  __syncthreads();
  if (tid < 2) {
    float acc = t2b[tid];
    for (int a = 0; a < 384; ++a) acc += hbuf[a] * t2W[a * 2 + tid];
    out[b * 2 + tid] = acc;                      // logits
  }
}

// ---------------------------------------------------------------------------
extern "C" void kernel_launch(void* const* d_in, const int* in_sizes, int n_in,
                              void* d_out, int out_size, void* d_ws, size_t ws_size,
                              hipStream_t stream) {
  const int*   ids    = (const int*)d_in[0];
  const int*   origin = (const int*)d_in[1];
  const float* tok    = (const float*)d_in[2];
  const float* pos    = (const float*)d_in[3];
  const float* saW    = (const float*)d_in[4];
  const float* sab    = (const float*)d_in[5];
  const float* smW    = (const float*)d_in[6];
  const float* smb    = (const float*)d_in[7];
  const float* Wq     = (const float*)d_in[8];
  const float* bq     = (const float*)d_in[9];
  const float* Wk     = (const float*)d_in[10];
  const float* bk     = (const float*)d_in[11];
  const float* Wv     = (const float*)d_in[12];
  const float* bv     = (const float*)d_in[13];
  const float* Wo     = (const float*)d_in[14];
  const float* bo     = (const float*)d_in[15];
  const float* lng    = (const float*)d_in[16];
  const float* lnb    = (const float*)d_in[17];
  const float* f1W    = (const float*)d_in[18];
  const float* f1b    = (const float*)d_in[19];
  const float* f2W    = (const float*)d_in[20];
  const float* f2bb   = (const float*)d_in[21];
  const float* t1W    = (const float*)d_in[22];
  const float* t1b    = (const float*)d_in[23];
  const float* t2W    = (const float*)d_in[24];
  const float* t2b    = (const float*)d_in[25];
  float* out = (float*)d_out;

  char* ws = (char*)d_ws;
  size_t off = 0;
  auto alloc = [&](size_t bytes) -> void* {
    void* p = ws + off;
    off += (bytes + 255) & ~(size_t)255;
    return p;
  };
  float* weff  = (float*)alloc(768 * 4);
  float* beff  = (float*)alloc(256);
  float* bqkv  = (float*)alloc(12 * 2304 * 4);
  float* x     = (float*)alloc((size_t)8192 * 768 * 4);
  u16*   xb    = (u16*)alloc((size_t)8192 * 768 * 2);
  u16*   big   = (u16*)alloc((size_t)8192 * 3072 * 2);   // qkv (8192x2304) / h1 (8192x3072)
  u16*   ctx   = (u16*)alloc((size_t)8192 * 768 * 2);
  u16*   vT    = (u16*)alloc((size_t)384 * 64 * 256 * 2);
  u16*   WqkvT = (u16*)alloc((size_t)2304 * 768 * 2);
  u16*   WoT   = (u16*)alloc((size_t)768 * 768 * 2);
  u16*   F1T   = (u16*)alloc((size_t)3072 * 768 * 2);
  u16*   F2T   = (u16*)alloc((size_t)768 * 3072 * 2);

  pack_bqkv<<<12, 256, 0, stream>>>(bq, bk, bv, bqkv);
  weff_kernel<<<3, 256, 0, stream>>>(saW, sab, smW, smb, weff, beff);
  embed_kernel<<<8192, 256, 0, stream>>>(ids, tok, pos, weff, beff, x, xb);

  for (int l = 0; l < 12; ++l) {
    prep_weights<<<6912, 256, 0, stream>>>(
        Wq + (size_t)l * 768 * 768, Wk + (size_t)l * 768 * 768,
        Wv + (size_t)l * 768 * 768, Wo + (size_t)l * 768 * 768,
        f1W + (size_t)l * 768 * 3072, f2W + (size_t)l * 3072 * 768,
        WqkvT, WoT, F1T, F2T);
    // QKV projection
    gemm_bt<0, 0, 0, 1><<<dim3(64, 18), 256, 0, stream>>>(
        xb, WqkvT, bqkv + l * 2304, nullptr, nullptr, big, 8192, 2304, 768);
    vtrans<<<6144, 256, 0, stream>>>(big, vT);
    attn_kernel<<<384, 256, 0, stream>>>(big, vT, origin, ctx);
    // Wo + residual (in-place into x, pre-LN)
    gemm_bt<0, 1, 1, 0><<<dim3(64, 6), 256, 0, stream>>>(
        ctx, WoT, bo + l * 768, x, x, nullptr, 8192, 768, 768);
    ln_kernel<<<8192, 256, 0, stream>>>(x, lng + l * 768, lnb + l * 768, xb);
    // FFN
    gemm_bt<1, 0, 0, 1><<<dim3(64, 24), 256, 0, stream>>>(
        xb, F1T, f1b + l * 3072, nullptr, nullptr, big, 8192, 3072, 768);
    gemm_bt<0, 0, 1, 1><<<dim3(64, 6), 256, 0, stream>>>(
        big, F2T, f2bb + l * 768, nullptr, x, xb, 8192, 768, 3072);
  }

  head_kernel<<<32, 256, 0, stream>>>(x, t1W, t1b, t2W, t2b, out);
}

// Round 6
// 3586.874 us; speedup vs baseline: 1.0062x; 1.0062x over previous
//
#include <hip/hip_runtime.h>
#include <stdint.h>

// ---------------------------------------------------------------------------
// BERT-style encoder forward, bf16 MFMA compute, f32 accumulate.
// B=32 S=256 K=6 D=768 H=12 DK=DV=64 DFF=3072 L=12 A=128 V=30000
// R5: dbuf K-loop (from R3-edit) + IMPROVED LDS XOR swizzle: chunk ^= (row>>1)&3
//     -> each 16-lane b128 phase hits all 8 LDS granules exactly 2x (free),
//     vs (row&3) variant's 4-way residual conflict.
// ---------------------------------------------------------------------------

typedef unsigned short u16;
typedef __attribute__((ext_vector_type(8))) __bf16 bf16x8;   // MFMA A/B operand (4 VGPR)
typedef __attribute__((ext_vector_type(4))) float f4;        // MFMA C/D operand

__device__ __forceinline__ u16 f2b(float f) {          // f32 -> bf16 RNE
  union { float f; uint32_t u; } v; v.f = f;
  uint32_t r = v.u + 0x7fffu + ((v.u >> 16) & 1u);
  return (u16)(r >> 16);
}

__device__ __forceinline__ void gload_lds16(const void* g, void* l) {
  __builtin_amdgcn_global_load_lds((const __attribute__((address_space(1))) uint32_t*)g,
                                   (__attribute__((address_space(3))) uint32_t*)l, 16, 0, 0);
}

__device__ __forceinline__ f4 mfma16(bf16x8 a, bf16x8 b, f4 c) {
  return __builtin_amdgcn_mfma_f32_16x16x32_bf16(a, b, c, 0, 0, 0);
}

// ---------------------------------------------------------------------------
// Generic bf16 GEMM: C[M,N] = A[M,K] * Bt[N,K]^T + bias (+res) (relu?) -> f32/bf16
// 128x128 tile, BK=32, 256 thr = 4 waves each 64x64.
// Double-buffered LDS: STAGE(next) issued before COMPUTE(cur); one
// vmcnt(0)+barrier per K-step. LDS slot (row,chunk) holds global chunk
// chunk ^ ((row>>1)&3) (chunk = 8-elem/16B group) -> per-phase granule-balanced.
// ---------------------------------------------------------------------------
template<int RELU, int RES, int WF32, int WB16>
__global__ __launch_bounds__(256, 2) void gemm_bt(
    const u16* __restrict__ A, const u16* __restrict__ Bt,
    const float* __restrict__ bias,
    const float* res, float* Cf, u16* Cb,
    int M, int N, int K)
{
  __shared__ __align__(16) u16 As[2][128 * 32];
  __shared__ __align__(16) u16 Bs[2][128 * 32];
  const int tid  = threadIdx.x;
  const int lane = tid & 63;
  const int w    = tid >> 6;
  const int wr   = w >> 1, wc = w & 1;
  const int m0   = blockIdx.x * 128;
  const int n0   = blockIdx.y * 128;

  f4 acc[4][4];
  const f4 zf = {0.f, 0.f, 0.f, 0.f};
#pragma unroll
  for (int i = 0; i < 4; ++i)
#pragma unroll
    for (int j = 0; j < 4; ++j) acc[i][j] = zf;

  // staging: LDS slot c = w*64 + lane = row c>>2, chunk c&3.
  // Source swizzle: that slot holds global chunk (c&3) ^ ((row>>1)&3),
  // (row>>1)&3 = (c>>3)&3. Rows +64 (gA1): (row>>1)&3 unchanged (+32).
  const int cA  = w * 64 + lane;
  const int rA  = cA >> 2;
  const int kc8 = ((cA & 3) ^ ((cA >> 3) & 3)) * 8;
  const u16* gA0 = A  + (long)(m0 + rA) * K + kc8;
  const u16* gA1 = gA0 + (long)64 * K;
  const u16* gB0 = Bt + (long)(n0 + rA) * K + kc8;
  const u16* gB1 = gB0 + (long)64 * K;

  // read swizzle: want chunk g=lane>>4 of row r (r&15 = lane&15; mf*16/wr*64
  // leave (r>>1)&3 = (lane>>1)&3 invariant): read slot g ^ ((lane>>1)&3).
  const int rdA = (wr * 64 + (lane & 15)) * 32 + (((lane >> 4) ^ ((lane >> 1) & 3))) * 8;
  const int rdB = (wc * 64 + (lane & 15)) * 32 + (((lane >> 4) ^ ((lane >> 1) & 3))) * 8;

  auto STAGE = [&](int buf) {
    gload_lds16(gA0, &As[buf][w * 512]);
    gload_lds16(gA1, &As[buf][w * 512 + 2048]);
    gload_lds16(gB0, &Bs[buf][w * 512]);
    gload_lds16(gB1, &Bs[buf][w * 512 + 2048]);
    gA0 += 32; gA1 += 32; gB0 += 32; gB1 += 32;
  };
  auto COMPUTE = [&](int buf) {
    bf16x8 af[4], bfr[4];
#pragma unroll
    for (int mf = 0; mf < 4; ++mf) af[mf] = *(const bf16x8*)&As[buf][rdA + mf * 512];
#pragma unroll
    for (int nf = 0; nf < 4; ++nf) bfr[nf] = *(const bf16x8*)&Bs[buf][rdB + nf * 512];
#pragma unroll
    for (int mf = 0; mf < 4; ++mf)
#pragma unroll
      for (int nf = 0; nf < 4; ++nf)
        acc[mf][nf] = mfma16(af[mf], bfr[nf], acc[mf][nf]);
  };

  const int nk = K >> 5;
  STAGE(0);
  asm volatile("s_waitcnt vmcnt(0)" ::: "memory");
  __syncthreads();
  int cur = 0;
  for (int kk = 0; kk < nk - 1; ++kk) {
    STAGE(cur ^ 1);              // prefetch next tile (overlaps compute below)
    COMPUTE(cur);
    asm volatile("s_waitcnt vmcnt(0)" ::: "memory");
    __syncthreads();
    cur ^= 1;
  }
  COMPUTE(cur);

  const int col0 = n0 + wc * 64 + (lane & 15);
  const int row0 = m0 + wr * 64 + (lane >> 4) * 4;
#pragma unroll
  for (int mf = 0; mf < 4; ++mf) {
#pragma unroll
    for (int nf = 0; nf < 4; ++nf) {
      const int col = col0 + nf * 16;
      const float bv = bias[col];
#pragma unroll
      for (int i = 0; i < 4; ++i) {
        const long r = row0 + mf * 16 + i;
        float v = acc[mf][nf][i] + bv;
        if (RES)  v += res[r * N + col];
        if (RELU) v  = fmaxf(v, 0.0f);
        if (WF32) Cf[r * N + col] = v;
        if (WB16) Cb[r * N + col] = f2b(v);
      }
    }
  }
}

// ---------------------------------------------------------------------------
// Weight prep: transpose f32 (R x C) -> bf16 (C x R), 32x32 tiles.
// One launch per layer covers Wq,Wk,Wv -> WqkvT ; Wo -> WoT ; f1 -> F1T ; f2 -> F2T
// ---------------------------------------------------------------------------
__device__ __forceinline__ void trans_tile(const float* __restrict__ src, u16* __restrict__ dst,
                                           int R, int C, int r0, int c0, int tid,
                                           float (*tile)[33])
{
  const int tx = tid & 31, ty = tid >> 5;
#pragma unroll
  for (int i = 0; i < 4; ++i)
    tile[ty + 8 * i][tx] = src[(long)(r0 + ty + 8 * i) * C + (c0 + tx)];
  __syncthreads();
#pragma unroll
  for (int i = 0; i < 4; ++i)
    dst[(long)(c0 + ty + 8 * i) * R + (r0 + tx)] = f2b(tile[tx][ty + 8 * i]);
}

__global__ __launch_bounds__(256) void prep_weights(
    const float* Wq, const float* Wk, const float* Wv, const float* Wo,
    const float* F1, const float* F2,
    u16* WqkvT, u16* WoT, u16* F1T, u16* F2T)
{
  __shared__ float tile[32][33];
  const int bid = blockIdx.x, tid = threadIdx.x;
  if (bid < 1728) {                 // Wq/Wk/Wv (768x768) -> rows [which*768, ..) of WqkvT
    const int which = bid / 576, t = bid % 576;
    const float* src = (which == 0) ? Wq : (which == 1) ? Wk : Wv;
    trans_tile(src, WqkvT + (long)which * 768 * 768, 768, 768,
               (t / 24) * 32, (t % 24) * 32, tid, tile);
  } else if (bid < 2304) {
    const int t = bid - 1728;
    trans_tile(Wo, WoT, 768, 768, (t / 24) * 32, (t % 24) * 32, tid, tile);
  } else if (bid < 4608) {
    const int t = bid - 2304;       // f1: 768 x 3072
    trans_tile(F1, F1T, 768, 3072, (t / 96) * 32, (t % 96) * 32, tid, tile);
  } else {
    const int t = bid - 4608;       // f2: 3072 x 768
    trans_tile(F2, F2T, 3072, 768, (t / 24) * 32, (t % 24) * 32, tid, tile);
  }
}

// ---------------------------------------------------------------------------
// V transpose: qkv[b*256+kpos][1536+h*64+d] -> vT[(b*12+h)*64+d][kpos]
// ---------------------------------------------------------------------------
__global__ __launch_bounds__(256) void vtrans(const u16* __restrict__ qkv, u16* __restrict__ vT)
{
  const int bid = blockIdx.x;          // 384 heads * 16 tiles
  const int bh = bid >> 4, t = bid & 15;
  const int b = bh / 12, h = bh % 12;
  const int tk = (t >> 1) * 32, td = (t & 1) * 32;
  __shared__ u16 tile[32][34];
  const int tx = threadIdx.x & 31, ty = threadIdx.x >> 5;
#pragma unroll
  for (int i = 0; i < 4; ++i)
    tile[ty + 8 * i][tx] = qkv[(long)(b * 256 + tk + ty + 8 * i) * 2304 + 1536 + h * 64 + td + tx];
  __syncthreads();
#pragma unroll
  for (int i = 0; i < 4; ++i)
    vT[((long)(bh * 64 + td + ty + 8 * i)) * 256 + tk + tx] = tile[tx][ty + 8 * i];
}

// ---------------------------------------------------------------------------
// Flash attention per (b,h). 4 waves x 64 q-rows. KVBLK=32, online softmax.
// Q/K frags read directly from global qkv (natural layout == B^T frag layout).
// V frags from vT. P: per-wave LDS round-trip (padded, conflict-light).
// ---------------------------------------------------------------------------
__global__ __launch_bounds__(256, 2) void attn_kernel(
    const u16* __restrict__ qkv, const u16* __restrict__ vT,
    const int* __restrict__ origin, u16* __restrict__ ctx)
{
  const int bh = blockIdx.x;
  const int b = bh / 12, h = bh % 12;
  const int tid = threadIdx.x, lane = tid & 63, w = tid >> 6;
  const int g = lane >> 4, c = lane & 15;
  __shared__ float mbias[256];
  __shared__ __align__(16) u16 Ps[4][64 * 40];
  mbias[tid] = (origin[b * 256 + tid] == 0) ? -1e9f : 0.0f;
  __syncthreads();

  // Q fragments: rows w*64 + mf*16 + c, dims ks*32 + g*8 + j
  bf16x8 qf[4][2];
  const long qbase = (long)(b * 256 + w * 64 + c) * 2304 + h * 64;
#pragma unroll
  for (int mf = 0; mf < 4; ++mf)
#pragma unroll
    for (int ks = 0; ks < 2; ++ks)
      qf[mf][ks] = *(const bf16x8*)&qkv[qbase + (long)mf * 16 * 2304 + ks * 32 + g * 8];

  f4 o[4][4];
  float mrun[4][4], lrun[4][4];
  const f4 zf = {0.f, 0.f, 0.f, 0.f};
#pragma unroll
  for (int i = 0; i < 4; ++i)
#pragma unroll
    for (int j = 0; j < 4; ++j) { o[i][j] = zf; mrun[i][j] = -1e30f; lrun[i][j] = 0.f; }

  u16* ps = Ps[w];
  const float scale = 0.125f;
  for (int kc = 0; kc < 8; ++kc) {
    bf16x8 kf[2][2];
#pragma unroll
    for (int nf = 0; nf < 2; ++nf)
#pragma unroll
      for (int ks = 0; ks < 2; ++ks)
        kf[nf][ks] = *(const bf16x8*)&qkv[(long)(b * 256 + kc * 32 + nf * 16 + c) * 2304
                                          + 768 + h * 64 + ks * 32 + g * 8];
    f4 s[4][2];
#pragma unroll
    for (int mf = 0; mf < 4; ++mf)
#pragma unroll
      for (int nf = 0; nf < 2; ++nf) {
        f4 t = mfma16(qf[mf][0], kf[nf][0], zf);
        s[mf][nf] = mfma16(qf[mf][1], kf[nf][1], t);
      }
    // online softmax update (row state per (mf,i), reduce over 16 lanes)
#pragma unroll
    for (int mf = 0; mf < 4; ++mf)
#pragma unroll
      for (int i = 0; i < 4; ++i) {
        float v0 = s[mf][0][i] * scale + mbias[kc * 32 + c];
        float v1 = s[mf][1][i] * scale + mbias[kc * 32 + 16 + c];
        float rm = fmaxf(v0, v1);
        rm = fmaxf(rm, __shfl_xor(rm, 1));
        rm = fmaxf(rm, __shfl_xor(rm, 2));
        rm = fmaxf(rm, __shfl_xor(rm, 4));
        rm = fmaxf(rm, __shfl_xor(rm, 8));
        const float mn   = fmaxf(mrun[mf][i], rm);
        const float corr = __expf(mrun[mf][i] - mn);
        mrun[mf][i] = mn;
        const float p0 = __expf(v0 - mn), p1 = __expf(v1 - mn);
        s[mf][0][i] = p0; s[mf][1][i] = p1;
        float rs = p0 + p1;
        rs += __shfl_xor(rs, 1);
        rs += __shfl_xor(rs, 2);
        rs += __shfl_xor(rs, 4);
        rs += __shfl_xor(rs, 8);
        lrun[mf][i] = lrun[mf][i] * corr + rs;
#pragma unroll
        for (int df = 0; df < 4; ++df) o[mf][df][i] *= corr;
      }
    // P (D-frag layout) -> LDS -> A-frag layout
#pragma unroll
    for (int mf = 0; mf < 4; ++mf)
#pragma unroll
      for (int nf = 0; nf < 2; ++nf)
#pragma unroll
        for (int i = 0; i < 4; ++i)
          ps[(mf * 16 + g * 4 + i) * 40 + nf * 16 + c] = f2b(s[mf][nf][i]);
    bf16x8 pa[4], vb[4];
#pragma unroll
    for (int mf = 0; mf < 4; ++mf) pa[mf] = *(const bf16x8*)&ps[(mf * 16 + c) * 40 + g * 8];
#pragma unroll
    for (int df = 0; df < 4; ++df)
      vb[df] = *(const bf16x8*)&vT[(long)(bh * 64 + df * 16 + c) * 256 + kc * 32 + g * 8];
#pragma unroll
    for (int mf = 0; mf < 4; ++mf)
#pragma unroll
      for (int df = 0; df < 4; ++df)
        o[mf][df] = mfma16(pa[mf], vb[df], o[mf][df]);
  }

#pragma unroll
  for (int mf = 0; mf < 4; ++mf)
#pragma unroll
    for (int i = 0; i < 4; ++i) {
      const float inv = 1.0f / lrun[mf][i];
      const long r = (long)(b * 256 + w * 64 + mf * 16 + g * 4 + i);
#pragma unroll
      for (int df = 0; df < 4; ++df)
        ctx[r * 768 + h * 64 + df * 16 + c] = f2b(o[mf][df][i] * inv);
    }
}

// ---------------------------------------------------------------------------
// LayerNorm over D=768, f32 in -> bf16 out. One block per row.
// ---------------------------------------------------------------------------
__global__ __launch_bounds__(256) void ln_kernel(const float* __restrict__ x,
    const float* __restrict__ gam, const float* __restrict__ bet, u16* __restrict__ out)
{
  const int row = blockIdx.x, tid = threadIdx.x;
  const int lane = tid & 63, w = tid >> 6;
  const float* xr = x + (long)row * 768;
  const float v0 = xr[tid], v1 = xr[tid + 256], v2 = xr[tid + 512];
  float s = v0 + v1 + v2;
#pragma unroll
  for (int off = 1; off < 64; off <<= 1) s += __shfl_xor(s, off);
  __shared__ float r1[4], r2[4];
  if (lane == 0) r1[w] = s;
  __syncthreads();
  const float mu = (r1[0] + r1[1] + r1[2] + r1[3]) * (1.0f / 768.0f);
  const float d0 = v0 - mu, d1 = v1 - mu, d2 = v2 - mu;
  float q = d0 * d0 + d1 * d1 + d2 * d2;
#pragma unroll
  for (int off = 1; off < 64; off <<= 1) q += __shfl_xor(q, off);
  if (lane == 0) r2[w] = q;
  __syncthreads();
  const float var = (r2[0] + r2[1] + r2[2] + r2[3]) * (1.0f / 768.0f);
  const float rs = rsqrtf(var + 1e-5f);
  out[(long)row * 768 + tid]       = f2b(d0 * rs * gam[tid]       + bet[tid]);
  out[(long)row * 768 + tid + 256] = f2b(d1 * rs * gam[tid + 256] + bet[tid + 256]);
  out[(long)row * 768 + tid + 512] = f2b(d2 * rs * gam[tid + 512] + bet[tid + 512]);
}

// ---------------------------------------------------------------------------
// Front-end: w_eff = sa_W @ sm_W (fold the linear soft-attention scorer)
// ---------------------------------------------------------------------------
__global__ void weff_kernel(const float* __restrict__ saW, const float* __restrict__ sab,
                            const float* __restrict__ smW, const float* __restrict__ smb,
                            float* weff, float* beff)
{
  const int d = blockIdx.x * 256 + threadIdx.x;   // grid 3 -> d in [0,768)
  float acc = 0.f;
  for (int a = 0; a < 128; ++a) acc += saW[d * 128 + a] * smW[a];
  weff[d] = acc;
  if (d == 0) {
    float bb = smb[0];
    for (int a = 0; a < 128; ++a) bb += sab[a] * smW[a];
    beff[0] = bb;
  }
}

// Embedding gather + K=6 soft-attention + positional add -> x (f32) and xb (bf16)
__global__ __launch_bounds__(256) void embed_kernel(
    const int* __restrict__ ids, const float* __restrict__ tok, const float* __restrict__ pos,
    const float* __restrict__ weff, const float* __restrict__ beff,
    float* __restrict__ x, u16* __restrict__ xb)
{
  const int m = blockIdx.x;           // b*256 + s
  const int s = m & 255;
  const int tid = threadIdx.x, lane = tid & 63, w = tid >> 6;
  __shared__ float emb[6][768];
  __shared__ float hred[6][4];
  const int* idp = ids + m * 6;
  float part[6];
#pragma unroll
  for (int k = 0; k < 6; ++k) {
    const float* e = tok + (long)idp[k] * 768;
    float p = 0.f;
#pragma unroll
    for (int j = 0; j < 3; ++j) {
      const int d = tid + j * 256;
      const float val = e[d];
      emb[k][d] = val;
      p += val * weff[d];
    }
    part[k] = p;
  }
#pragma unroll
  for (int k = 0; k < 6; ++k) {
    float p = part[k];
#pragma unroll
    for (int off = 1; off < 64; off <<= 1) p += __shfl_xor(p, off);
    if (lane == 0) hred[k][w] = p;
  }
  __syncthreads();
  float hv[6], mx = -1e30f;
#pragma unroll
  for (int k = 0; k < 6; ++k) {
    hv[k] = hred[k][0] + hred[k][1] + hred[k][2] + hred[k][3] + beff[0];
    mx = fmaxf(mx, hv[k]);
  }
  float esum = 0.f;
#pragma unroll
  for (int k = 0; k < 6; ++k) { hv[k] = __expf(hv[k] - mx); esum += hv[k]; }
  const float inv = 1.0f / esum;
#pragma unroll
  for (int j = 0; j < 3; ++j) {
    const int d = tid + j * 256;
    float acc = pos[s * 768 + d];
#pragma unroll
    for (int k = 0; k < 6; ++k) acc += hv[k] * inv * emb[k][d];
    x[(long)m * 768 + d] = acc;
    xb[(long)m * 768 + d] = f2b(acc);
  }
}

__global__ void pack_bqkv(const float* __restrict__ bq, const float* __restrict__ bk,
                          const float* __restrict__ bv, float* __restrict__ bqkv)
{
  const int l = blockIdx.x;
  for (int n = threadIdx.x; n < 2304; n += 256) {
    float v = (n < 768) ? bq[l * 768 + n] : (n < 1536) ? bk[l * 768 + n - 768]
                                                       : bv[l * 768 + n - 1536];
    bqkv[l * 2304 + n] = v;
  }
}

// Final head: rep = x[:,0,:]; logits = relu(rep@t1W+t1b)@t2W+t2b. f32.
__global__ __launch_bounds__(256) void head_kernel(const float* __restrict__ x,
    const float* __restrict__ t1W, const float* __restrict__ t1b,
    const float* __restrict__ t2W, const float* __restrict__ t2b,
    float* __restrict__ out)
{
  const int b = blockIdx.x, tid = threadIdx.x;
  __shared__ float rep[768];
  __shared__ float hbuf[384];
  const float* xr = x + (long)b * 256 * 768;     // row b*256
  for (int d = tid; d < 768; d += 256) {
    const float v = xr[d];
    rep[d] = v;
    out[64 + b * 768 + d] = v;                   // rep output
  }
  __syncthreads();
  for (int j = tid; j < 384; j += 256) {
    float acc = t1b[j];
    for (int d = 0; d < 768; ++d) acc += rep[d] * t1W[(long)d * 384 + j];
    hbuf[j] = fmaxf(acc, 0.0f);
  }
  __syncthreads();
  if (tid < 2) {
    float acc = t2b[tid];
    for (int a = 0; a < 384; ++a) acc += hbuf[a] * t2W[a * 2 + tid];
    out[b * 2 + tid] = acc;                      // logits
  }
}

// ---------------------------------------------------------------------------
extern "C" void kernel_launch(void* const* d_in, const int* in_sizes, int n_in,
                              void* d_out, int out_size, void* d_ws, size_t ws_size,
                              hipStream_t stream) {
  const int*   ids    = (const int*)d_in[0];
  const int*   origin = (const int*)d_in[1];
  const float* tok    = (const float*)d_in[2];
  const float* pos    = (const float*)d_in[3];
  const float* saW    = (const float*)d_in[4];
  const float* sab    = (const float*)d_in[5];
  const float* smW    = (const float*)d_in[6];
  const float* smb    = (const float*)d_in[7];
  const float* Wq     = (const float*)d_in[8];
  const float* bq     = (const float*)d_in[9];
  const float* Wk     = (const float*)d_in[10];
  const float* bk     = (const float*)d_in[11];
  const float* Wv     = (const float*)d_in[12];
  const float* bv     = (const float*)d_in[13];
  const float* Wo     = (const float*)d_in[14];
  const float* bo     = (const float*)d_in[15];
  const float* lng    = (const float*)d_in[16];
  const float* lnb    = (const float*)d_in[17];
  const float* f1W    = (const float*)d_in[18];
  const float* f1b    = (const float*)d_in[19];
  const float* f2W    = (const float*)d_in[20];
  const float* f2bb   = (const float*)d_in[21];
  const float* t1W    = (const float*)d_in[22];
  const float* t1b    = (const float*)d_in[23];
  const float* t2W    = (const float*)d_in[24];
  const float* t2b    = (const float*)d_in[25];
  float* out = (float*)d_out;

  char* ws = (char*)d_ws;
  size_t off = 0;
  auto alloc = [&](size_t bytes) -> void* {
    void* p = ws + off;
    off += (bytes + 255) & ~(size_t)255;
    return p;
  };
  float* weff  = (float*)alloc(768 * 4);
  float* beff  = (float*)alloc(256);
  float* bqkv  = (float*)alloc(12 * 2304 * 4);
  float* x     = (float*)alloc((size_t)8192 * 768 * 4);
  u16*   xb    = (u16*)alloc((size_t)8192 * 768 * 2);
  u16*   big   = (u16*)alloc((size_t)8192 * 3072 * 2);   // qkv (8192x2304) / h1 (8192x3072)
  u16*   ctx   = (u16*)alloc((size_t)8192 * 768 * 2);
  u16*   vT    = (u16*)alloc((size_t)384 * 64 * 256 * 2);
  u16*   WqkvT = (u16*)alloc((size_t)2304 * 768 * 2);
  u16*   WoT   = (u16*)alloc((size_t)768 * 768 * 2);
  u16*   F1T   = (u16*)alloc((size_t)3072 * 768 * 2);
  u16*   F2T   = (u16*)alloc((size_t)768 * 3072 * 2);

  pack_bqkv<<<12, 256, 0, stream>>>(bq, bk, bv, bqkv);
  weff_kernel<<<3, 256, 0, stream>>>(saW, sab, smW, smb, weff, beff);
  embed_kernel<<<8192, 256, 0, stream>>>(ids, tok, pos, weff, beff, x, xb);

  for (int l = 0; l < 12; ++l) {
    prep_weights<<<6912, 256, 0, stream>>>(
        Wq + (size_t)l * 768 * 768, Wk + (size_t)l * 768 * 768,
        Wv + (size_t)l * 768 * 768, Wo + (size_t)l * 768 * 768,
        f1W + (size_t)l * 768 * 3072, f2W + (size_t)l * 3072 * 768,
        WqkvT, WoT, F1T, F2T);
    // QKV projection
    gemm_bt<0, 0, 0, 1><<<dim3(64, 18), 256, 0, stream>>>(
        xb, WqkvT, bqkv + l * 2304, nullptr, nullptr, big, 8192, 2304, 768);
    vtrans<<<6144, 256, 0, stream>>>(big, vT);
    attn_kernel<<<384, 256, 0, stream>>>(big, vT, origin, ctx);
    // Wo + residual (in-place into x, pre-LN)
    gemm_bt<0, 1, 1, 0><<<dim3(64, 6), 256, 0, stream>>>(
        ctx, WoT, bo + l * 768, x, x, nullptr, 8192, 768, 768);
    ln_kernel<<<8192, 256, 0, stream>>>(x, lng + l * 768, lnb + l * 768, xb);
    // FFN
    gemm_bt<1, 0, 0, 1><<<dim3(64, 24), 256, 0, stream>>>(
        xb, F1T, f1b + l * 3072, nullptr, nullptr, big, 8192, 3072, 768);
    gemm_bt<0, 0, 1, 1><<<dim3(64, 6), 256, 0, stream>>>(
        big, F2T, f2bb + l * 768, nullptr, x, xb, 8192, 768, 3072);
  }

  head_kernel<<<32, 256, 0, stream>>>(x, t1W, t1b, t2W, t2b, out);
}

// Round 7
// 3533.344 us; speedup vs baseline: 1.0215x; 1.0152x over previous
//
#include <hip/hip_runtime.h>
#include <stdint.h>

// ---------------------------------------------------------------------------
// BERT-style encoder forward, bf16 MFMA compute, f32 accumulate.
// B=32 S=256 K=6 D=768 H=12 DK=DV=64 DFF=3072 L=12 A=128 V=30000
// R7: counted-vmcnt 2-stage-ahead pipeline with RAW s_barrier (no compiler
//     vmcnt(0) drain — R6 showed __syncthreads drains the prefetch every
//     K-step: conflicts 4.7M->0 but MfmaUtil only 21%). Swizzle kept.
// ---------------------------------------------------------------------------

typedef unsigned short u16;
typedef __attribute__((ext_vector_type(8))) __bf16 bf16x8;   // MFMA A/B operand (4 VGPR)
typedef __attribute__((ext_vector_type(4))) float f4;        // MFMA C/D operand

__device__ __forceinline__ u16 f2b(float f) {          // f32 -> bf16 RNE
  union { float f; uint32_t u; } v; v.f = f;
  uint32_t r = v.u + 0x7fffu + ((v.u >> 16) & 1u);
  return (u16)(r >> 16);
}

__device__ __forceinline__ void gload_lds16(const void* g, void* l) {
  __builtin_amdgcn_global_load_lds((const __attribute__((address_space(1))) uint32_t*)g,
                                   (__attribute__((address_space(3))) uint32_t*)l, 16, 0, 0);
}

__device__ __forceinline__ f4 mfma16(bf16x8 a, bf16x8 b, f4 c) {
  return __builtin_amdgcn_mfma_f32_16x16x32_bf16(a, b, c, 0, 0, 0);
}

// ---------------------------------------------------------------------------
// Generic bf16 GEMM: C[M,N] = A[M,K] * Bt[N,K]^T + bias (+res) (relu?) -> f32/bf16
// 128x128 tile, BK=32, 256 thr = 4 waves each 64x64.
// Pipeline (T3+T4): STAGE(0),STAGE(1) up front; per K-step
//   vmcnt(4) [stage k done, k+1 in flight] -> s_barrier -> ds_read+MFMA ->
//   lgkmcnt(0) -> s_barrier -> STAGE(k+2).
// Loads span a full compute phase; vmcnt never drains to 0 mid-loop.
// LDS slot (row,chunk) holds global chunk chunk^((row>>1)&3): granule-balanced.
// ---------------------------------------------------------------------------
template<int RELU, int RES, int WF32, int WB16>
__global__ __launch_bounds__(256, 2) void gemm_bt(
    const u16* __restrict__ A, const u16* __restrict__ Bt,
    const float* __restrict__ bias,
    const float* res, float* Cf, u16* Cb,
    int M, int N, int K)
{
  __shared__ __align__(16) u16 As[2][128 * 32];
  __shared__ __align__(16) u16 Bs[2][128 * 32];
  const int tid  = threadIdx.x;
  const int lane = tid & 63;
  const int w    = tid >> 6;
  const int wr   = w >> 1, wc = w & 1;
  const int m0   = blockIdx.x * 128;
  const int n0   = blockIdx.y * 128;

  f4 acc[4][4];
  const f4 zf = {0.f, 0.f, 0.f, 0.f};
#pragma unroll
  for (int i = 0; i < 4; ++i)
#pragma unroll
    for (int j = 0; j < 4; ++j) acc[i][j] = zf;

  // staging: LDS slot c = w*64 + lane = row c>>2, chunk c&3.
  // Source swizzle: that slot holds global chunk (c&3) ^ ((row>>1)&3).
  const int cA  = w * 64 + lane;
  const int rA  = cA >> 2;
  const int kc8 = ((cA & 3) ^ ((cA >> 3) & 3)) * 8;
  const u16* gA0 = A  + (long)(m0 + rA) * K + kc8;
  const u16* gA1 = gA0 + (long)64 * K;
  const u16* gB0 = Bt + (long)(n0 + rA) * K + kc8;
  const u16* gB1 = gB0 + (long)64 * K;

  // read swizzle: chunk g=lane>>4 of row r -> slot g ^ ((lane>>1)&3).
  const int rdA = (wr * 64 + (lane & 15)) * 32 + (((lane >> 4) ^ ((lane >> 1) & 3))) * 8;
  const int rdB = (wc * 64 + (lane & 15)) * 32 + (((lane >> 4) ^ ((lane >> 1) & 3))) * 8;

  auto STAGE = [&](int buf) {
    gload_lds16(gA0, &As[buf][w * 512]);
    gload_lds16(gA1, &As[buf][w * 512 + 2048]);
    gload_lds16(gB0, &Bs[buf][w * 512]);
    gload_lds16(gB1, &Bs[buf][w * 512 + 2048]);
    gA0 += 32; gA1 += 32; gB0 += 32; gB1 += 32;
  };
  auto COMPUTE = [&](int buf) {
    bf16x8 af[4], bfr[4];
#pragma unroll
    for (int mf = 0; mf < 4; ++mf) af[mf] = *(const bf16x8*)&As[buf][rdA + mf * 512];
#pragma unroll
    for (int nf = 0; nf < 4; ++nf) bfr[nf] = *(const bf16x8*)&Bs[buf][rdB + nf * 512];
#pragma unroll
    for (int mf = 0; mf < 4; ++mf)
#pragma unroll
      for (int nf = 0; nf < 4; ++nf)
        acc[mf][nf] = mfma16(af[mf], bfr[nf], acc[mf][nf]);
  };

  const int nk = K >> 5;          // >= 24 for all call sites
  STAGE(0);
  STAGE(1);
  for (int kk = 0; kk < nk; ++kk) {
    // wait for stage kk only; stage kk+1 (4 loads) stays in flight
    if (kk + 1 < nk) asm volatile("s_waitcnt vmcnt(4)" ::: "memory");
    else             asm volatile("s_waitcnt vmcnt(0)" ::: "memory");
    __builtin_amdgcn_sched_barrier(0);
    __builtin_amdgcn_s_barrier();          // all waves' stage-kk writes visible
    COMPUTE(kk & 1);
    asm volatile("s_waitcnt lgkmcnt(0)" ::: "memory");  // ds_reads landed in VGPRs
    __builtin_amdgcn_sched_barrier(0);
    __builtin_amdgcn_s_barrier();          // safe to overwrite buf kk&1
    if (kk + 2 < nk) STAGE(kk & 1);        // buf (kk+2)&1 == kk&1
  }

  const int col0 = n0 + wc * 64 + (lane & 15);
  const int row0 = m0 + wr * 64 + (lane >> 4) * 4;
#pragma unroll
  for (int mf = 0; mf < 4; ++mf) {
#pragma unroll
    for (int nf = 0; nf < 4; ++nf) {
      const int col = col0 + nf * 16;
      const float bv = bias[col];
#pragma unroll
      for (int i = 0; i < 4; ++i) {
        const long r = row0 + mf * 16 + i;
        float v = acc[mf][nf][i] + bv;
        if (RES)  v += res[r * N + col];
        if (RELU) v  = fmaxf(v, 0.0f);
        if (WF32) Cf[r * N + col] = v;
        if (WB16) Cb[r * N + col] = f2b(v);
      }
    }
  }
}

// ---------------------------------------------------------------------------
// Weight prep: transpose f32 (R x C) -> bf16 (C x R), 32x32 tiles.
// One launch per layer covers Wq,Wk,Wv -> WqkvT ; Wo -> WoT ; f1 -> F1T ; f2 -> F2T
// ---------------------------------------------------------------------------
__device__ __forceinline__ void trans_tile(const float* __restrict__ src, u16* __restrict__ dst,
                                           int R, int C, int r0, int c0, int tid,
                                           float (*tile)[33])
{
  const int tx = tid & 31, ty = tid >> 5;
#pragma unroll
  for (int i = 0; i < 4; ++i)
    tile[ty + 8 * i][tx] = src[(long)(r0 + ty + 8 * i) * C + (c0 + tx)];
  __syncthreads();
#pragma unroll
  for (int i = 0; i < 4; ++i)
    dst[(long)(c0 + ty + 8 * i) * R + (r0 + tx)] = f2b(tile[tx][ty + 8 * i]);
}

__global__ __launch_bounds__(256) void prep_weights(
    const float* Wq, const float* Wk, const float* Wv, const float* Wo,
    const float* F1, const float* F2,
    u16* WqkvT, u16* WoT, u16* F1T, u16* F2T)
{
  __shared__ float tile[32][33];
  const int bid = blockIdx.x, tid = threadIdx.x;
  if (bid < 1728) {                 // Wq/Wk/Wv (768x768) -> rows [which*768, ..) of WqkvT
    const int which = bid / 576, t = bid % 576;
    const float* src = (which == 0) ? Wq : (which == 1) ? Wk : Wv;
    trans_tile(src, WqkvT + (long)which * 768 * 768, 768, 768,
               (t / 24) * 32, (t % 24) * 32, tid, tile);
  } else if (bid < 2304) {
    const int t = bid - 1728;
    trans_tile(Wo, WoT, 768, 768, (t / 24) * 32, (t % 24) * 32, tid, tile);
  } else if (bid < 4608) {
    const int t = bid - 2304;       // f1: 768 x 3072
    trans_tile(F1, F1T, 768, 3072, (t / 96) * 32, (t % 96) * 32, tid, tile);
  } else {
    const int t = bid - 4608;       // f2: 3072 x 768
    trans_tile(F2, F2T, 3072, 768, (t / 24) * 32, (t % 24) * 32, tid, tile);
  }
}

// ---------------------------------------------------------------------------
// V transpose: qkv[b*256+kpos][1536+h*64+d] -> vT[(b*12+h)*64+d][kpos]
// ---------------------------------------------------------------------------
__global__ __launch_bounds__(256) void vtrans(const u16* __restrict__ qkv, u16* __restrict__ vT)
{
  const int bid = blockIdx.x;          // 384 heads * 16 tiles
  const int bh = bid >> 4, t = bid & 15;
  const int b = bh / 12, h = bh % 12;
  const int tk = (t >> 1) * 32, td = (t & 1) * 32;
  __shared__ u16 tile[32][34];
  const int tx = threadIdx.x & 31, ty = threadIdx.x >> 5;
#pragma unroll
  for (int i = 0; i < 4; ++i)
    tile[ty + 8 * i][tx] = qkv[(long)(b * 256 + tk + ty + 8 * i) * 2304 + 1536 + h * 64 + td + tx];
  __syncthreads();
#pragma unroll
  for (int i = 0; i < 4; ++i)
    vT[((long)(bh * 64 + td + ty + 8 * i)) * 256 + tk + tx] = tile[tx][ty + 8 * i];
}

// ---------------------------------------------------------------------------
// Flash attention per (b,h). 4 waves x 64 q-rows. KVBLK=32, online softmax.
// Q/K frags read directly from global qkv (natural layout == B^T frag layout).
// V frags from vT. P: per-wave LDS round-trip (padded, conflict-light).
// ---------------------------------------------------------------------------
__global__ __launch_bounds__(256, 2) void attn_kernel(
    const u16* __restrict__ qkv, const u16* __restrict__ vT,
    const int* __restrict__ origin, u16* __restrict__ ctx)
{
  const int bh = blockIdx.x;
  const int b = bh / 12, h = bh % 12;
  const int tid = threadIdx.x, lane = tid & 63, w = tid >> 6;
  const int g = lane >> 4, c = lane & 15;
  __shared__ float mbias[256];
  __shared__ __align__(16) u16 Ps[4][64 * 40];
  mbias[tid] = (origin[b * 256 + tid] == 0) ? -1e9f : 0.0f;
  __syncthreads();

  // Q fragments: rows w*64 + mf*16 + c, dims ks*32 + g*8 + j
  bf16x8 qf[4][2];
  const long qbase = (long)(b * 256 + w * 64 + c) * 2304 + h * 64;
#pragma unroll
  for (int mf = 0; mf < 4; ++mf)
#pragma unroll
    for (int ks = 0; ks < 2; ++ks)
      qf[mf][ks] = *(const bf16x8*)&qkv[qbase + (long)mf * 16 * 2304 + ks * 32 + g * 8];

  f4 o[4][4];
  float mrun[4][4], lrun[4][4];
  const f4 zf = {0.f, 0.f, 0.f, 0.f};
#pragma unroll
  for (int i = 0; i < 4; ++i)
#pragma unroll
    for (int j = 0; j < 4; ++j) { o[i][j] = zf; mrun[i][j] = -1e30f; lrun[i][j] = 0.f; }

  u16* ps = Ps[w];
  const float scale = 0.125f;
  for (int kc = 0; kc < 8; ++kc) {
    bf16x8 kf[2][2];
#pragma unroll
    for (int nf = 0; nf < 2; ++nf)
#pragma unroll
      for (int ks = 0; ks < 2; ++ks)
        kf[nf][ks] = *(const bf16x8*)&qkv[(long)(b * 256 + kc * 32 + nf * 16 + c) * 2304
                                          + 768 + h * 64 + ks * 32 + g * 8];
    f4 s[4][2];
#pragma unroll
    for (int mf = 0; mf < 4; ++mf)
#pragma unroll
      for (int nf = 0; nf < 2; ++nf) {
        f4 t = mfma16(qf[mf][0], kf[nf][0], zf);
        s[mf][nf] = mfma16(qf[mf][1], kf[nf][1], t);
      }
    // online softmax update (row state per (mf,i), reduce over 16 lanes)
#pragma unroll
    for (int mf = 0; mf < 4; ++mf)
#pragma unroll
      for (int i = 0; i < 4; ++i) {
        float v0 = s[mf][0][i] * scale + mbias[kc * 32 + c];
        float v1 = s[mf][1][i] * scale + mbias[kc * 32 + 16 + c];
        float rm = fmaxf(v0, v1);
        rm = fmaxf(rm, __shfl_xor(rm, 1));
        rm = fmaxf(rm, __shfl_xor(rm, 2));
        rm = fmaxf(rm, __shfl_xor(rm, 4));
        rm = fmaxf(rm, __shfl_xor(rm, 8));
        const float mn   = fmaxf(mrun[mf][i], rm);
        const float corr = __expf(mrun[mf][i] - mn);
        mrun[mf][i] = mn;
        const float p0 = __expf(v0 - mn), p1 = __expf(v1 - mn);
        s[mf][0][i] = p0; s[mf][1][i] = p1;
        float rs = p0 + p1;
        rs += __shfl_xor(rs, 1);
        rs += __shfl_xor(rs, 2);
        rs += __shfl_xor(rs, 4);
        rs += __shfl_xor(rs, 8);
        lrun[mf][i] = lrun[mf][i] * corr + rs;
#pragma unroll
        for (int df = 0; df < 4; ++df) o[mf][df][i] *= corr;
      }
    // P (D-frag layout) -> LDS -> A-frag layout
#pragma unroll
    for (int mf = 0; mf < 4; ++mf)
#pragma unroll
      for (int nf = 0; nf < 2; ++nf)
#pragma unroll
        for (int i = 0; i < 4; ++i)
          ps[(mf * 16 + g * 4 + i) * 40 + nf * 16 + c] = f2b(s[mf][nf][i]);
    bf16x8 pa[4], vb[4];
#pragma unroll
    for (int mf = 0; mf < 4; ++mf) pa[mf] = *(const bf16x8*)&ps[(mf * 16 + c) * 40 + g * 8];
#pragma unroll
    for (int df = 0; df < 4; ++df)
      vb[df] = *(const bf16x8*)&vT[(long)(bh * 64 + df * 16 + c) * 256 + kc * 32 + g * 8];
#pragma unroll
    for (int mf = 0; mf < 4; ++mf)
#pragma unroll
      for (int df = 0; df < 4; ++df)
        o[mf][df] = mfma16(pa[mf], vb[df], o[mf][df]);
  }

#pragma unroll
  for (int mf = 0; mf < 4; ++mf)
#pragma unroll
    for (int i = 0; i < 4; ++i) {
      const float inv = 1.0f / lrun[mf][i];
      const long r = (long)(b * 256 + w * 64 + mf * 16 + g * 4 + i);
#pragma unroll
      for (int df = 0; df < 4; ++df)
        ctx[r * 768 + h * 64 + df * 16 + c] = f2b(o[mf][df][i] * inv);
    }
}

// ---------------------------------------------------------------------------
// LayerNorm over D=768, f32 in -> bf16 out. One block per row.
// ---------------------------------------------------------------------------
__global__ __launch_bounds__(256) void ln_kernel(const float* __restrict__ x,
    const float* __restrict__ gam, const float* __restrict__ bet, u16* __restrict__ out)
{
  const int row = blockIdx.x, tid = threadIdx.x;
  const int lane = tid & 63, w = tid >> 6;
  const float* xr = x + (long)row * 768;
  const float v0 = xr[tid], v1 = xr[tid + 256], v2 = xr[tid + 512];
  float s = v0 + v1 + v2;
#pragma unroll
  for (int off = 1; off < 64; off <<= 1) s += __shfl_xor(s, off);
  __shared__ float r1[4], r2[4];
  if (lane == 0) r1[w] = s;
  __syncthreads();
  const float mu = (r1[0] + r1[1] + r1[2] + r1[3]) * (1.0f / 768.0f);
  const float d0 = v0 - mu, d1 = v1 - mu, d2 = v2 - mu;
  float q = d0 * d0 + d1 * d1 + d2 * d2;
#pragma unroll
  for (int off = 1; off < 64; off <<= 1) q += __shfl_xor(q, off);
  if (lane == 0) r2[w] = q;
  __syncthreads();
  const float var = (r2[0] + r2[1] + r2[2] + r2[3]) * (1.0f / 768.0f);
  const float rs = rsqrtf(var + 1e-5f);
  out[(long)row * 768 + tid]       = f2b(d0 * rs * gam[tid]       + bet[tid]);
  out[(long)row * 768 + tid + 256] = f2b(d1 * rs * gam[tid + 256] + bet[tid + 256]);
  out[(long)row * 768 + tid + 512] = f2b(d2 * rs * gam[tid + 512] + bet[tid + 512]);
}

// ---------------------------------------------------------------------------
// Front-end: w_eff = sa_W @ sm_W (fold the linear soft-attention scorer)
// ---------------------------------------------------------------------------
__global__ void weff_kernel(const float* __restrict__ saW, const float* __restrict__ sab,
                            const float* __restrict__ smW, const float* __restrict__ smb,
                            float* weff, float* beff)
{
  const int d = blockIdx.x * 256 + threadIdx.x;   // grid 3 -> d in [0,768)
  float acc = 0.f;
  for (int a = 0; a < 128; ++a) acc += saW[d * 128 + a] * smW[a];
  weff[d] = acc;
  if (d == 0) {
    float bb = smb[0];
    for (int a = 0; a < 128; ++a) bb += sab[a] * smW[a];
    beff[0] = bb;
  }
}

// Embedding gather + K=6 soft-attention + positional add -> x (f32) and xb (bf16)
__global__ __launch_bounds__(256) void embed_kernel(
    const int* __restrict__ ids, const float* __restrict__ tok, const float* __restrict__ pos,
    const float* __restrict__ weff, const float* __restrict__ beff,
    float* __restrict__ x, u16* __restrict__ xb)
{
  const int m = blockIdx.x;           // b*256 + s
  const int s = m & 255;
  const int tid = threadIdx.x, lane = tid & 63, w = tid >> 6;
  __shared__ float emb[6][768];
  __shared__ float hred[6][4];
  const int* idp = ids + m * 6;
  float part[6];
#pragma unroll
  for (int k = 0; k < 6; ++k) {
    const float* e = tok + (long)idp[k] * 768;
    float p = 0.f;
#pragma unroll
    for (int j = 0; j < 3; ++j) {
      const int d = tid + j * 256;
      const float val = e[d];
      emb[k][d] = val;
      p += val * weff[d];
    }
    part[k] = p;
  }
#pragma unroll
  for (int k = 0; k < 6; ++k) {
    float p = part[k];
#pragma unroll
    for (int off = 1; off < 64; off <<= 1) p += __shfl_xor(p, off);
    if (lane == 0) hred[k][w] = p;
  }
  __syncthreads();
  float hv[6], mx = -1e30f;
#pragma unroll
  for (int k = 0; k < 6; ++k) {
    hv[k] = hred[k][0] + hred[k][1] + hred[k][2] + hred[k][3] + beff[0];
    mx = fmaxf(mx, hv[k]);
  }
  float esum = 0.f;
#pragma unroll
  for (int k = 0; k < 6; ++k) { hv[k] = __expf(hv[k] - mx); esum += hv[k]; }
  const float inv = 1.0f / esum;
#pragma unroll
  for (int j = 0; j < 3; ++j) {
    const int d = tid + j * 256;
    float acc = pos[s * 768 + d];
#pragma unroll
    for (int k = 0; k < 6; ++k) acc += hv[k] * inv * emb[k][d];
    x[(long)m * 768 + d] = acc;
    xb[(long)m * 768 + d] = f2b(acc);
  }
}

__global__ void pack_bqkv(const float* __restrict__ bq, const float* __restrict__ bk,
                          const float* __restrict__ bv, float* __restrict__ bqkv)
{
  const int l = blockIdx.x;
  for (int n = threadIdx.x; n < 2304; n += 256) {
    float v = (n < 768) ? bq[l * 768 + n] : (n < 1536) ? bk[l * 768 + n - 768]
                                                       : bv[l * 768 + n - 1536];
    bqkv[l * 2304 + n] = v;
  }
}

// Final head: rep = x[:,0,:]; logits = relu(rep@t1W+t1b)@t2W+t2b. f32.
__global__ __launch_bounds__(256) void head_kernel(const float* __restrict__ x,
    const float* __restrict__ t1W, const float* __restrict__ t1b,
    const float* __restrict__ t2W, const float* __restrict__ t2b,
    float* __restrict__ out)
{
  const int b = blockIdx.x, tid = threadIdx.x;
  __shared__ float rep[768];
  __shared__ float hbuf[384];
  const float* xr = x + (long)b * 256 * 768;     // row b*256
  for (int d = tid; d < 768; d += 256) {
    const float v = xr[d];
    rep[d] = v;
    out[64 + b * 768 + d] = v;                   // rep output
  }
  __syncthreads();
  for (int j = tid; j < 384; j += 256) {
    float acc = t1b[j];
    for (int d = 0; d < 768; ++d) acc += rep[d] * t1W[(long)d * 384 + j];
    hbuf[j] = fmaxf(acc, 0.0f);
  }
  __syncthreads();
  if (tid < 2) {
    float acc = t2b[tid];
    for (int a = 0; a < 384; ++a) acc += hbuf[a] * t2W[a * 2 + tid];
    out[b * 2 + tid] = acc;                      // logits
  }
}

// ---------------------------------------------------------------------------
extern "C" void kernel_launch(void* const* d_in, const int* in_sizes, int n_in,
                              void* d_out, int out_size, void* d_ws, size_t ws_size,
                              hipStream_t stream) {
  const int*   ids    = (const int*)d_in[0];
  const int*   origin = (const int*)d_in[1];
  const float* tok    = (const float*)d_in[2];
  const float* pos    = (const float*)d_in[3];
  const float* saW    = (const float*)d_in[4];
  const float* sab    = (const float*)d_in[5];
  const float* smW    = (const float*)d_in[6];
  const float* smb    = (const float*)d_in[7];
  const float* Wq     = (const float*)d_in[8];
  const float* bq     = (const float*)d_in[9];
  const float* Wk     = (const float*)d_in[10];
  const float* bk     = (const float*)d_in[11];
  const float* Wv     = (const float*)d_in[12];
  const float* bv     = (const float*)d_in[13];
  const float* Wo     = (const float*)d_in[14];
  const float* bo     = (const float*)d_in[15];
  const float* lng    = (const float*)d_in[16];
  const float* lnb    = (const float*)d_in[17];
  const float* f1W    = (const float*)d_in[18];
  const float* f1b    = (const float*)d_in[19];
  const float* f2W    = (const float*)d_in[20];
  const float* f2bb   = (const float*)d_in[21];
  const float* t1W    = (const float*)d_in[22];
  const float* t1b    = (const float*)d_in[23];
  const float* t2W    = (const float*)d_in[24];
  const float* t2b    = (const float*)d_in[25];
  float* out = (float*)d_out;

  char* ws = (char*)d_ws;
  size_t off = 0;
  auto alloc = [&](size_t bytes) -> void* {
    void* p = ws + off;
    off += (bytes + 255) & ~(size_t)255;
    return p;
  };
  float* weff  = (float*)alloc(768 * 4);
  float* beff  = (float*)alloc(256);
  float* bqkv  = (float*)alloc(12 * 2304 * 4);
  float* x     = (float*)alloc((size_t)8192 * 768 * 4);
  u16*   xb    = (u16*)alloc((size_t)8192 * 768 * 2);
  u16*   big   = (u16*)alloc((size_t)8192 * 3072 * 2);   // qkv (8192x2304) / h1 (8192x3072)
  u16*   ctx   = (u16*)alloc((size_t)8192 * 768 * 2);
  u16*   vT    = (u16*)alloc((size_t)384 * 64 * 256 * 2);
  u16*   WqkvT = (u16*)alloc((size_t)2304 * 768 * 2);
  u16*   WoT   = (u16*)alloc((size_t)768 * 768 * 2);
  u16*   F1T   = (u16*)alloc((size_t)3072 * 768 * 2);
  u16*   F2T   = (u16*)alloc((size_t)768 * 3072 * 2);

  pack_bqkv<<<12, 256, 0, stream>>>(bq, bk, bv, bqkv);
  weff_kernel<<<3, 256, 0, stream>>>(saW, sab, smW, smb, weff, beff);
  embed_kernel<<<8192, 256, 0, stream>>>(ids, tok, pos, weff, beff, x, xb);

  for (int l = 0; l < 12; ++l) {
    prep_weights<<<6912, 256, 0, stream>>>(
        Wq + (size_t)l * 768 * 768, Wk + (size_t)l * 768 * 768,
        Wv + (size_t)l * 768 * 768, Wo + (size_t)l * 768 * 768,
        f1W + (size_t)l * 768 * 3072, f2W + (size_t)l * 3072 * 768,
        WqkvT, WoT, F1T, F2T);
    // QKV projection
    gemm_bt<0, 0, 0, 1><<<dim3(64, 18), 256, 0, stream>>>(
        xb, WqkvT, bqkv + l * 2304, nullptr, nullptr, big, 8192, 2304, 768);
    vtrans<<<6144, 256, 0, stream>>>(big, vT);
    attn_kernel<<<384, 256, 0, stream>>>(big, vT, origin, ctx);
    // Wo + residual (in-place into x, pre-LN)
    gemm_bt<0, 1, 1, 0><<<dim3(64, 6), 256, 0, stream>>>(
        ctx, WoT, bo + l * 768, x, x, nullptr, 8192, 768, 768);
    ln_kernel<<<8192, 256, 0, stream>>>(x, lng + l * 768, lnb + l * 768, xb);
    // FFN
    gemm_bt<1, 0, 0, 1><<<dim3(64, 24), 256, 0, stream>>>(
        xb, F1T, f1b + l * 3072, nullptr, nullptr, big, 8192, 3072, 768);
    gemm_bt<0, 0, 1, 1><<<dim3(64, 6), 256, 0, stream>>>(
        big, F2T, f2bb + l * 768, nullptr, x, xb, 8192, 768, 3072);
  }

  head_kernel<<<32, 256, 0, stream>>>(x, t1W, t1b, t2W, t2b, out);
}